// Round 15
// baseline (264.942 us; speedup 1.0000x reference)
//
#include <hip/hip_runtime.h>

#define NN 20000
#define DD 128
#define HH 128
#define G4 512
#define DEG 32
#define NG 1250    // groups of 16 nodes; one WAVE per group, barrier-free scan

typedef __attribute__((ext_vector_type(4))) float f32x4;
typedef __attribute__((ext_vector_type(8))) short s16x8;

#ifndef __has_builtin
#define __has_builtin(x) 0
#endif

// Builtin transcendentals ONLY (round-9 lesson: raw inline-asm v_exp/v_rcp bypasses
// the compiler's trans-use hazard handling -> numerical corruption).
static __device__ __forceinline__ float fexp2(float x){
#if __has_builtin(__builtin_amdgcn_exp2f)
  return __builtin_amdgcn_exp2f(x);
#else
  return exp2f(x);
#endif
}
static __device__ __forceinline__ float frcp(float x){
#if __has_builtin(__builtin_amdgcn_rcpf)
  return __builtin_amdgcn_rcpf(x);
#else
  return 1.f/x;
#endif
}

// packed f32x2 -> bf16x2 (RNE) — VOP3, no trans hazard; proven since round 1
static __device__ __forceinline__ unsigned cvt_pk_bf16(float lo, float hi){
  unsigned r;
  asm("v_cvt_pk_bf16_f32 %0, %1, %2" : "=v"(r) : "v"(lo), "v"(hi));
  return r;
}
static __device__ __forceinline__ s16x8 ld8bf(const float* __restrict__ p){
  f32x4 a = *(const f32x4*)p;
  f32x4 b = *(const f32x4*)(p+4);
  union{unsigned u[4]; s16x8 v;} z;
  z.u[0]=cvt_pk_bf16(a[0],a[1]);
  z.u[1]=cvt_pk_bf16(a[2],a[3]);
  z.u[2]=cvt_pk_bf16(b[0],b[1]);
  z.u[3]=cvt_pk_bf16(b[2],b[3]);
  return z.v;
}
// scaled variant: multiply by s before bf16 conversion (log2e pre-scaling)
static __device__ __forceinline__ s16x8 ld8bf_s(const float* __restrict__ p, float s){
  f32x4 a = *(const f32x4*)p;
  f32x4 b = *(const f32x4*)(p+4);
  union{unsigned u[4]; s16x8 v;} z;
  z.u[0]=cvt_pk_bf16(a[0]*s,a[1]*s);
  z.u[1]=cvt_pk_bf16(a[2]*s,a[3]*s);
  z.u[2]=cvt_pk_bf16(b[0]*s,b[1]*s);
  z.u[3]=cvt_pk_bf16(b[2]*s,b[3]*s);
  return z.v;
}
// bf16 packed in u32 -> f32 (bf16 in high 16 bits IS the f32 bit pattern)
static __device__ __forceinline__ float lo16f(unsigned u){
  union{unsigned x; float f;} v; v.x = u << 16; return v.f;
}
static __device__ __forceinline__ float hi16f(unsigned u){
  union{unsigned x; float f;} v; v.x = u & 0xffff0000u; return v.f;
}
#define NLOG2E -1.44269504f
#define TLOG2E  2.88539008f

// ---------------- Phase 1: Hp = (h @ W_ih^T + b_ih + b_hh) * S[gate], bf16 ----------------
// PERMUTED layout: element (n, gate g, dim d=16w+4hi+r) stored at n*512 + w*64 + hi*16 + g*4 + r.
// PRE-SCALED by S = {-log2e, -log2e, 2log2e, -log2e} per gate (acc feeds exp2 directly).
// (unchanged from round 10 — the scan's gather reads this layout natively)
__global__ __launch_bounds__(512,2) void k_hp(
    const float* __restrict__ h, const float* __restrict__ W_ih,
    const float* __restrict__ b_ih, const float* __restrict__ b_hh,
    unsigned short* __restrict__ Hp)
{
  const int tid=threadIdx.x, w=tid>>6, lane=tid&63, lo=lane&15, hi=lane>>4;
  const float SC[4]={NLOG2E,NLOG2E,TLOG2E,NLOG2E};
  s16x8 A[4][4];
#pragma unroll
  for(int g=0;g<4;++g){
    const float* wr=W_ih+(size_t)(128*g+16*w+lo)*DD+8*hi;
#pragma unroll
    for(int c=0;c<4;++c) A[g][c]=ld8bf_s(wr+32*c, SC[g]);
  }
  f32x4 bb[4];
#pragma unroll
  for(int g=0;g<4;++g){
    const int gcb=128*g+16*w+4*hi;
    bb[g]=(*(const f32x4*)(b_ih+gcb) + *(const f32x4*)(b_hh+gcb))*SC[g];
  }
  const int nchunk = (blockIdx.x < 57) ? 2 : 1;
  for(int cc=0; cc<nchunk; ++cc){
    const int n0 = ((cc? 256+blockIdx.x : blockIdx.x))*64;
    f32x4 acc[4][4];
#pragma unroll
    for(int g=0;g<4;++g)
#pragma unroll
      for(int nt=0;nt<4;++nt) acc[g][nt]=(f32x4)0.f;
#pragma unroll
    for(int c=0;c<4;++c){
      s16x8 B[4];
#pragma unroll
      for(int nt=0;nt<4;++nt){
        int nd=n0+16*nt+lo; if(nd>=NN) nd=NN-1;
        B[nt]=ld8bf(h+(size_t)nd*DD+32*c+8*hi);
      }
#pragma unroll
      for(int g=0;g<4;++g)
#pragma unroll
        for(int nt=0;nt<4;++nt)
          acc[g][nt]=__builtin_amdgcn_mfma_f32_16x16x32_bf16(A[g][c],B[nt],acc[g][nt],0,0,0);
    }
#pragma unroll
    for(int nt=0;nt<4;++nt){
      int nd=n0+16*nt+lo;
      if(nd<NN){
        unsigned short* p = Hp + (size_t)nd*G4 + w*64 + hi*16;
        uint4 q0, q1;
        q0.x=cvt_pk_bf16(acc[0][nt][0]+bb[0][0], acc[0][nt][1]+bb[0][1]);
        q0.y=cvt_pk_bf16(acc[0][nt][2]+bb[0][2], acc[0][nt][3]+bb[0][3]);
        q0.z=cvt_pk_bf16(acc[1][nt][0]+bb[1][0], acc[1][nt][1]+bb[1][1]);
        q0.w=cvt_pk_bf16(acc[1][nt][2]+bb[1][2], acc[1][nt][3]+bb[1][3]);
        q1.x=cvt_pk_bf16(acc[2][nt][0]+bb[2][0], acc[2][nt][1]+bb[2][1]);
        q1.y=cvt_pk_bf16(acc[2][nt][2]+bb[2][2], acc[2][nt][3]+bb[2][3]);
        q1.z=cvt_pk_bf16(acc[3][nt][0]+bb[3][0], acc[3][nt][1]+bb[3][1]);
        q1.w=cvt_pk_bf16(acc[3][nt][2]+bb[3][2], acc[3][nt][3]+bb[3][3]);
        *(uint4*)p = q0;
        *(uint4*)(p+8) = q1;
      }
    }
  }
}

// ---------------- Phase 2: WAVE-AUTONOMOUS LSTM scan — zero barriers in the t-loop ----------
// Grid 256 x 512 (1 block/CU, 160KB LDS). LDS: [0,128K) = full W_hh, bf16, prescaled,
// XOR-swizzled rows; [128K,160K) = 8 x 4KB per-wave h buffers. Each WAVE owns one
// 16-node group (grp = w*256 + blockIdx -> 4-5 active waves on EVERY CU). Per t:
// B = h(t-1) from own LDS slice; A streamed from the shared W_hh image (128 ds_read_b128,
// swizzle-conflict-free); 128 MFMA in two 64-reg halves; lane-local r10 cell
// (lane owns dims 16*db+4*hi+r of its 16 nodes); h(t) written back. DS ops are in-order
// per wave, so no s_barrier is needed anywhere in the scan.
__global__ __launch_bounds__(512,1) void k_scan(
    const float* __restrict__ h, const int* __restrict__ nbr,
    const float* __restrict__ W_hh, const unsigned short* __restrict__ Hp,
    const float* __restrict__ W_out, const float* __restrict__ b_out,
    float* __restrict__ out)
{
  extern __shared__ char smem[];             // 163840 B
  const int tid=threadIdx.x, w=tid>>6, lane=tid&63, lo=lane&15, hi=lane>>4;

  // ---- stage W_hh: thread tid stages row r=tid (prescaled, swizzled) ----
  {
    const int r=tid;
    const float s = ((r>>7)==2) ? TLOG2E : NLOG2E;
    const float* wr = W_hh + (size_t)r*HH;
    const int sw = (r&7)<<4;
#pragma unroll
    for(int j=0;j<16;++j){
      s16x8 v = ld8bf_s(wr + 8*j, s);
      *(s16x8*)(smem + ((r*256 + j*16) ^ sw)) = v;
    }
  }
  __syncthreads();

  const int grp = w*256 + blockIdx.x;
  if(grp >= NG) return;                      // idle waves exit (no later barriers)
  const int n0 = grp*16;

  const int swz=(lo&7)<<4;
  char* hreg = smem + 131072 + w*4096;       // this wave's h buffer (16 nodes x 128 dims bf16)
  // lane-invariant LDS read bases (64c folded inside the XOR; m*4096 added above swz bits)
  const char* rdA[4]; const char* rdB[4];
#pragma unroll
  for(int c=0;c<4;++c){
    const int off = (lo*256 + 64*c + 16*hi) ^ swz;
    rdA[c] = smem + off;
    rdB[c] = hreg + off;
  }
  // zero h(-1)
#pragma unroll
  for(int i=0;i<4;++i){
    uint4 z4={0u,0u,0u,0u};
    *(uint4*)(hreg + lane*16 + i*1024) = z4;
  }

  float cst[32];                             // C-state (x 2log2e), dims db*4+r
#pragma unroll
  for(int i=0;i<32;++i) cst[i]=0.f;

  const int* nbp = nbr + (size_t)(n0 + lo)*DEG;
  int idx_cur = nbp[0];

#pragma unroll 1
  for(int t=0;t<DEG;++t){
    int tn=(t+1<DEG)? t+1 : t;
    int idx_next = nbp[tn];
    // gather this step's Hp chunks: 8 x 32B per lane (layout matches k_hp natively)
    const char* gp = (const char*)Hp + (size_t)(unsigned)idx_cur*1024 + hi*32;
    uint4 q[16];
#pragma unroll
    for(int db=0;db<8;++db){
      q[2*db  ]=*(const uint4*)(gp + db*128);
      q[2*db+1]=*(const uint4*)(gp + db*128 + 16);
    }
    // B fragments: full h(t-1) (read BEFORE any h(t) writes)
    s16x8 B[4];
#pragma unroll
    for(int c=0;c<4;++c) B[c]=*(const s16x8*)(rdB[c]);

#pragma unroll
    for(int half=0;half<2;++half){
      // acc init from gather + MFMA over the half's 16 tiles
      f32x4 acc[4][4];                       // [gate][dbL]
#pragma unroll
      for(int g=0;g<4;++g)
#pragma unroll
        for(int dl=0;dl<4;++dl){
          const uint4& a=q[2*(dl+4*half)];
          const uint4& b=q[2*(dl+4*half)+1];
          if(g==0){ acc[0][dl][0]=lo16f(a.x); acc[0][dl][1]=hi16f(a.x); acc[0][dl][2]=lo16f(a.y); acc[0][dl][3]=hi16f(a.y); }
          if(g==1){ acc[1][dl][0]=lo16f(a.z); acc[1][dl][1]=hi16f(a.z); acc[1][dl][2]=lo16f(a.w); acc[1][dl][3]=hi16f(a.w); }
          if(g==2){ acc[2][dl][0]=lo16f(b.x); acc[2][dl][1]=hi16f(b.x); acc[2][dl][2]=lo16f(b.y); acc[2][dl][3]=hi16f(b.y); }
          if(g==3){ acc[3][dl][0]=lo16f(b.z); acc[3][dl][1]=hi16f(b.z); acc[3][dl][2]=lo16f(b.w); acc[3][dl][3]=hi16f(b.w); }
        }
#pragma unroll
      for(int c=0;c<4;++c)
#pragma unroll
        for(int g=0;g<4;++g)
#pragma unroll
          for(int dl=0;dl<4;++dl){
            const int m = g*8 + dl + 4*half; // tile m: W rows 128g + 16(dl+4*half) ..+15
            s16x8 Af = *(const s16x8*)(rdA[c] + m*4096);
            acc[g][dl]=__builtin_amdgcn_mfma_f32_16x16x32_bf16(Af,B[c],acc[g][dl],0,0,0);
          }
      // lane-local cell (r10-proven math) + h(t) write for this half's dims
#pragma unroll
      for(int dl=0;dl<4;++dl){
        const int db = dl + 4*half;
        float hv[4];
#pragma unroll
        for(int r=0;r<4;++r){
          float ei=fexp2(acc[0][dl][r]);
          float ef=fexp2(acc[1][dl][r]);
          float eg=fexp2(acc[2][dl][r]);
          float eo=fexp2(acc[3][dl][r]);
          float itgT=__builtin_fmaf(eg, TLOG2E, -TLOG2E)*frcp((1.f+ei)*(1.f+eg));
          float Cn=__builtin_fmaf(cst[db*4+r], frcp(1.f+ef), itgT);
          cst[db*4+r]=Cn;
          float ec=fexp2(Cn);
          hv[r]=(ec-1.f)*frcp((1.f+eo)*(1.f+ec));
        }
        uint2 pk;
        pk.x=cvt_pk_bf16(hv[0],hv[1]);
        pk.y=cvt_pk_bf16(hv[2],hv[3]);
        *(uint2*)(hreg + ((lo*256 + 32*db + 8*hi) ^ swz)) = pk;
      }
    }
    idx_cur = idx_next;
  }

  // ---- fused output projection: out = relu([h, agg] @ W_out^T + b_out) ----
  // agg = h(31), resident in this wave's hreg.
  s16x8 BB[8];
#pragma unroll
  for(int c=0;c<4;++c) BB[c]=ld8bf(h + (size_t)(n0+lo)*DD + 32*c + 8*hi);
#pragma unroll
  for(int c=0;c<4;++c) BB[4+c]=*(const s16x8*)(rdB[c]);
  f32x4 po[8];
#pragma unroll
  for(int m=0;m<8;++m) po[m]=(f32x4)0.f;
#pragma unroll
  for(int m=0;m<8;++m)
#pragma unroll
    for(int c=0;c<8;++c){
      s16x8 Af=ld8bf(W_out + (size_t)(16*m+lo)*256 + 32*c + 8*hi);
      po[m]=__builtin_amdgcn_mfma_f32_16x16x32_bf16(Af,BB[c],po[m],0,0,0);
    }
#pragma unroll
  for(int m=0;m<8;++m){
    f32x4 bias=*(const f32x4*)(b_out + 16*m + 4*hi);
#pragma unroll
    for(int r=0;r<4;++r){ float v=po[m][r]+bias[r]; po[m][r]=v>0.f?v:0.f; }
    *(f32x4*)(out + (size_t)(n0+lo)*HH + 16*m + 4*hi)=po[m];
  }
}

extern "C" void kernel_launch(void* const* d_in, const int* in_sizes, int n_in,
                              void* d_out, int out_size, void* d_ws, size_t ws_size,
                              hipStream_t stream)
{
  const float* h     = (const float*)d_in[0];
  const int*   nbr   = (const int*)d_in[1];
  const float* W_ih  = (const float*)d_in[2];
  const float* W_hh  = (const float*)d_in[3];
  const float* b_ih  = (const float*)d_in[4];
  const float* b_hh  = (const float*)d_in[5];
  const float* W_out = (const float*)d_in[6];
  const float* b_out = (const float*)d_in[7];
  unsigned short* Hp = (unsigned short*)d_ws;   // 20000*512*2B = 20.48 MB

  k_hp<<<256, 512, 0, stream>>>(h, W_ih, b_ih, b_hh, Hp);
  k_scan<<<256, 512, 163840, stream>>>(h, nbr, W_hh, Hp, W_out, b_out, (float*)d_out);
}

// Round 16
// 235.292 us; speedup vs baseline: 1.1260x; 1.1260x over previous
//
#include <hip/hip_runtime.h>

#define NN 20000
#define DD 128
#define HH 128
#define G4 512
#define DEG 32
#define NG 1250    // groups of 16 nodes; one WAVE per group, barrier-free scan

typedef __attribute__((ext_vector_type(4))) float f32x4;
typedef __attribute__((ext_vector_type(8))) short s16x8;

#ifndef __has_builtin
#define __has_builtin(x) 0
#endif

// Builtin transcendentals ONLY (round-9 lesson: raw inline-asm v_exp/v_rcp bypasses
// the compiler's trans-use hazard handling -> numerical corruption).
static __device__ __forceinline__ float fexp2(float x){
#if __has_builtin(__builtin_amdgcn_exp2f)
  return __builtin_amdgcn_exp2f(x);
#else
  return exp2f(x);
#endif
}
static __device__ __forceinline__ float frcp(float x){
#if __has_builtin(__builtin_amdgcn_rcpf)
  return __builtin_amdgcn_rcpf(x);
#else
  return 1.f/x;
#endif
}

// packed f32x2 -> bf16x2 (RNE) — VOP3, no trans hazard; proven since round 1
static __device__ __forceinline__ unsigned cvt_pk_bf16(float lo, float hi){
  unsigned r;
  asm("v_cvt_pk_bf16_f32 %0, %1, %2" : "=v"(r) : "v"(lo), "v"(hi));
  return r;
}
static __device__ __forceinline__ s16x8 ld8bf(const float* __restrict__ p){
  f32x4 a = *(const f32x4*)p;
  f32x4 b = *(const f32x4*)(p+4);
  union{unsigned u[4]; s16x8 v;} z;
  z.u[0]=cvt_pk_bf16(a[0],a[1]);
  z.u[1]=cvt_pk_bf16(a[2],a[3]);
  z.u[2]=cvt_pk_bf16(b[0],b[1]);
  z.u[3]=cvt_pk_bf16(b[2],b[3]);
  return z.v;
}
// scaled variant: multiply by s before bf16 conversion (log2e pre-scaling)
static __device__ __forceinline__ s16x8 ld8bf_s(const float* __restrict__ p, float s){
  f32x4 a = *(const f32x4*)p;
  f32x4 b = *(const f32x4*)(p+4);
  union{unsigned u[4]; s16x8 v;} z;
  z.u[0]=cvt_pk_bf16(a[0]*s,a[1]*s);
  z.u[1]=cvt_pk_bf16(a[2]*s,a[3]*s);
  z.u[2]=cvt_pk_bf16(b[0]*s,b[1]*s);
  z.u[3]=cvt_pk_bf16(b[2]*s,b[3]*s);
  return z.v;
}
// bf16 packed in u32 -> f32 (bf16 in high 16 bits IS the f32 bit pattern)
static __device__ __forceinline__ float lo16f(unsigned u){
  union{unsigned x; float f;} v; v.x = u << 16; return v.f;
}
static __device__ __forceinline__ float hi16f(unsigned u){
  union{unsigned x; float f;} v; v.x = u & 0xffff0000u; return v.f;
}
#define NLOG2E -1.44269504f
#define TLOG2E  2.88539008f

// ---------------- Phase 1: Hp = (h @ W_ih^T + b_ih + b_hh) * S[gate], bf16 ----------------
// PERMUTED layout: element (n, gate g, dim d=16w+4hi+r) stored at n*512 + w*64 + hi*16 + g*4 + r.
// PRE-SCALED by S = {-log2e, -log2e, 2log2e, -log2e} per gate (acc feeds exp2 directly).
__global__ __launch_bounds__(512,2) void k_hp(
    const float* __restrict__ h, const float* __restrict__ W_ih,
    const float* __restrict__ b_ih, const float* __restrict__ b_hh,
    unsigned short* __restrict__ Hp)
{
  const int tid=threadIdx.x, w=tid>>6, lane=tid&63, lo=lane&15, hi=lane>>4;
  const float SC[4]={NLOG2E,NLOG2E,TLOG2E,NLOG2E};
  s16x8 A[4][4];
#pragma unroll
  for(int g=0;g<4;++g){
    const float* wr=W_ih+(size_t)(128*g+16*w+lo)*DD+8*hi;
#pragma unroll
    for(int c=0;c<4;++c) A[g][c]=ld8bf_s(wr+32*c, SC[g]);
  }
  f32x4 bb[4];
#pragma unroll
  for(int g=0;g<4;++g){
    const int gcb=128*g+16*w+4*hi;
    bb[g]=(*(const f32x4*)(b_ih+gcb) + *(const f32x4*)(b_hh+gcb))*SC[g];
  }
  const int nchunk = (blockIdx.x < 57) ? 2 : 1;
  for(int cc=0; cc<nchunk; ++cc){
    const int n0 = ((cc? 256+blockIdx.x : blockIdx.x))*64;
    f32x4 acc[4][4];
#pragma unroll
    for(int g=0;g<4;++g)
#pragma unroll
      for(int nt=0;nt<4;++nt) acc[g][nt]=(f32x4)0.f;
#pragma unroll
    for(int c=0;c<4;++c){
      s16x8 B[4];
#pragma unroll
      for(int nt=0;nt<4;++nt){
        int nd=n0+16*nt+lo; if(nd>=NN) nd=NN-1;
        B[nt]=ld8bf(h+(size_t)nd*DD+32*c+8*hi);
      }
#pragma unroll
      for(int g=0;g<4;++g)
#pragma unroll
        for(int nt=0;nt<4;++nt)
          acc[g][nt]=__builtin_amdgcn_mfma_f32_16x16x32_bf16(A[g][c],B[nt],acc[g][nt],0,0,0);
    }
#pragma unroll
    for(int nt=0;nt<4;++nt){
      int nd=n0+16*nt+lo;
      if(nd<NN){
        unsigned short* p = Hp + (size_t)nd*G4 + w*64 + hi*16;
        uint4 q0, q1;
        q0.x=cvt_pk_bf16(acc[0][nt][0]+bb[0][0], acc[0][nt][1]+bb[0][1]);
        q0.y=cvt_pk_bf16(acc[0][nt][2]+bb[0][2], acc[0][nt][3]+bb[0][3]);
        q0.z=cvt_pk_bf16(acc[1][nt][0]+bb[1][0], acc[1][nt][1]+bb[1][1]);
        q0.w=cvt_pk_bf16(acc[1][nt][2]+bb[1][2], acc[1][nt][3]+bb[1][3]);
        q1.x=cvt_pk_bf16(acc[2][nt][0]+bb[2][0], acc[2][nt][1]+bb[2][1]);
        q1.y=cvt_pk_bf16(acc[2][nt][2]+bb[2][2], acc[2][nt][3]+bb[2][3]);
        q1.z=cvt_pk_bf16(acc[3][nt][0]+bb[3][0], acc[3][nt][1]+bb[3][1]);
        q1.w=cvt_pk_bf16(acc[3][nt][2]+bb[3][2], acc[3][nt][3]+bb[3][3]);
        *(uint4*)p = q0;
        *(uint4*)(p+8) = q1;
      }
    }
  }
}

// ---------------- Phase 2: WAVE-AUTONOMOUS LSTM scan — zero barriers in the t-loop ----------
// Identical structure to round 15 (verified correct) with ONE change: the W_hh fragment
// stream uses an explicit 8-deep circular register buffer (Afb), so each MFMA's Af was
// ds_read 8 ops earlier (~135 cy dep distance >= LDS latency). Round 15's compiler
// schedule issued read->MFMA back-to-back per tile, eating ~120 cy x 128 tiles/t.
__global__ __launch_bounds__(512,1) void k_scan(
    const float* __restrict__ h, const int* __restrict__ nbr,
    const float* __restrict__ W_hh, const unsigned short* __restrict__ Hp,
    const float* __restrict__ W_out, const float* __restrict__ b_out,
    float* __restrict__ out)
{
  extern __shared__ char smem[];             // 163840 B
  const int tid=threadIdx.x, w=tid>>6, lane=tid&63, lo=lane&15, hi=lane>>4;

  // ---- stage W_hh: thread tid stages row r=tid (prescaled, swizzled) ----
  {
    const int r=tid;
    const float s = ((r>>7)==2) ? TLOG2E : NLOG2E;
    const float* wr = W_hh + (size_t)r*HH;
    const int sw = (r&7)<<4;
#pragma unroll
    for(int j=0;j<16;++j){
      s16x8 v = ld8bf_s(wr + 8*j, s);
      *(s16x8*)(smem + ((r*256 + j*16) ^ sw)) = v;
    }
  }
  __syncthreads();

  const int grp = w*256 + blockIdx.x;
  if(grp >= NG) return;                      // idle waves exit (no later barriers)
  const int n0 = grp*16;

  const int swz=(lo&7)<<4;
  char* hreg = smem + 131072 + w*4096;       // this wave's h buffer (16 nodes x 128 dims bf16)
  const char* rdA[4]; const char* rdB[4];
#pragma unroll
  for(int c=0;c<4;++c){
    const int off = (lo*256 + 64*c + 16*hi) ^ swz;
    rdA[c] = smem + off;
    rdB[c] = hreg + off;
  }
  // zero h(-1)
#pragma unroll
  for(int i=0;i<4;++i){
    uint4 z4={0u,0u,0u,0u};
    *(uint4*)(hreg + lane*16 + i*1024) = z4;
  }

  float cst[32];                             // C-state (x 2log2e), dims db*4+r
#pragma unroll
  for(int i=0;i<32;++i) cst[i]=0.f;

  const int* nbp = nbr + (size_t)(n0 + lo)*DEG;
  int idx_cur = nbp[0];

#pragma unroll 1
  for(int t=0;t<DEG;++t){
    int tn=(t+1<DEG)? t+1 : t;
    int idx_next = nbp[tn];
    // gather this step's Hp chunks: 8 x 32B per lane (layout matches k_hp natively)
    const char* gp = (const char*)Hp + (size_t)(unsigned)idx_cur*1024 + hi*32;
    uint4 q[16];
#pragma unroll
    for(int db=0;db<8;++db){
      q[2*db  ]=*(const uint4*)(gp + db*128);
      q[2*db+1]=*(const uint4*)(gp + db*128 + 16);
    }
    // B fragments: full h(t-1) (read BEFORE any h(t) writes)
    s16x8 B[4];
#pragma unroll
    for(int c=0;c<4;++c) B[c]=*(const s16x8*)(rdB[c]);

#pragma unroll
    for(int half=0;half<2;++half){
      // acc init from gather
      f32x4 acc[4][4];                       // [gate][dl]
#pragma unroll
      for(int dl=0;dl<4;++dl){
        const uint4& a=q[2*(dl+4*half)];
        const uint4& b=q[2*(dl+4*half)+1];
        acc[0][dl][0]=lo16f(a.x); acc[0][dl][1]=hi16f(a.x); acc[0][dl][2]=lo16f(a.y); acc[0][dl][3]=hi16f(a.y);
        acc[1][dl][0]=lo16f(a.z); acc[1][dl][1]=hi16f(a.z); acc[1][dl][2]=lo16f(a.w); acc[1][dl][3]=hi16f(a.w);
        acc[2][dl][0]=lo16f(b.x); acc[2][dl][1]=hi16f(b.x); acc[2][dl][2]=lo16f(b.y); acc[2][dl][3]=hi16f(b.y);
        acc[3][dl][0]=lo16f(b.z); acc[3][dl][1]=hi16f(b.z); acc[3][dl][2]=lo16f(b.w); acc[3][dl][3]=hi16f(b.w);
      }
      // ---- software-pipelined W_hh stream: 64 ops j=(tile tj)*4+c, Afb depth 8 ----
      // tile tj -> (g=tj>>2, dl=tj&3), m = g*8 + dl + 4*half; addr = rdA[c] + m*4096.
      // Accumulation order per acc[g][dl] is c=0,1,2,3 — identical to round 15 (bit-exact).
#define AFADDR(J) (rdA[(J)&3] + (((((J)>>2)>>2)*8 + (((J)>>2)&3) + 4*half)*4096))
      s16x8 Afb[8];
#pragma unroll
      for(int j=0;j<8;++j) Afb[j]=*(const s16x8*)AFADDR(j);
#pragma unroll
      for(int j=0;j<64;++j){
        const int tj=j>>2, g=tj>>2, dl=tj&3;
        acc[g][dl]=__builtin_amdgcn_mfma_f32_16x16x32_bf16(Afb[j&7],B[j&3],acc[g][dl],0,0,0);
        if(j+8<64) Afb[j&7]=*(const s16x8*)AFADDR(j+8);
      }
#undef AFADDR
      // lane-local cell (r10-proven math) + h(t) write for this half's dims
#pragma unroll
      for(int dl=0;dl<4;++dl){
        const int db = dl + 4*half;
        float hv[4];
#pragma unroll
        for(int r=0;r<4;++r){
          float ei=fexp2(acc[0][dl][r]);
          float ef=fexp2(acc[1][dl][r]);
          float eg=fexp2(acc[2][dl][r]);
          float eo=fexp2(acc[3][dl][r]);
          float itgT=__builtin_fmaf(eg, TLOG2E, -TLOG2E)*frcp((1.f+ei)*(1.f+eg));
          float Cn=__builtin_fmaf(cst[db*4+r], frcp(1.f+ef), itgT);
          cst[db*4+r]=Cn;
          float ec=fexp2(Cn);
          hv[r]=(ec-1.f)*frcp((1.f+eo)*(1.f+ec));
        }
        uint2 pk;
        pk.x=cvt_pk_bf16(hv[0],hv[1]);
        pk.y=cvt_pk_bf16(hv[2],hv[3]);
        *(uint2*)(hreg + ((lo*256 + 32*db + 8*hi) ^ swz)) = pk;
      }
    }
    idx_cur = idx_next;
  }

  // ---- fused output projection: out = relu([h, agg] @ W_out^T + b_out) ----
  s16x8 BB[8];
#pragma unroll
  for(int c=0;c<4;++c) BB[c]=ld8bf(h + (size_t)(n0+lo)*DD + 32*c + 8*hi);
#pragma unroll
  for(int c=0;c<4;++c) BB[4+c]=*(const s16x8*)(rdB[c]);
  f32x4 po[8];
#pragma unroll
  for(int m=0;m<8;++m) po[m]=(f32x4)0.f;
#pragma unroll
  for(int m=0;m<8;++m)
#pragma unroll
    for(int c=0;c<8;++c){
      s16x8 Af=ld8bf(W_out + (size_t)(16*m+lo)*256 + 32*c + 8*hi);
      po[m]=__builtin_amdgcn_mfma_f32_16x16x32_bf16(Af,BB[c],po[m],0,0,0);
    }
#pragma unroll
  for(int m=0;m<8;++m){
    f32x4 bias=*(const f32x4*)(b_out + 16*m + 4*hi);
#pragma unroll
    for(int r=0;r<4;++r){ float v=po[m][r]+bias[r]; po[m][r]=v>0.f?v:0.f; }
    *(f32x4*)(out + (size_t)(n0+lo)*HH + 16*m + 4*hi)=po[m];
  }
}

extern "C" void kernel_launch(void* const* d_in, const int* in_sizes, int n_in,
                              void* d_out, int out_size, void* d_ws, size_t ws_size,
                              hipStream_t stream)
{
  const float* h     = (const float*)d_in[0];
  const int*   nbr   = (const int*)d_in[1];
  const float* W_ih  = (const float*)d_in[2];
  const float* W_hh  = (const float*)d_in[3];
  const float* b_ih  = (const float*)d_in[4];
  const float* b_hh  = (const float*)d_in[5];
  const float* W_out = (const float*)d_in[6];
  const float* b_out = (const float*)d_in[7];
  unsigned short* Hp = (unsigned short*)d_ws;   // 20000*512*2B = 20.48 MB

  k_hp<<<256, 512, 0, stream>>>(h, W_ih, b_ih, b_hh, Hp);
  k_scan<<<256, 512, 163840, stream>>>(h, nbr, W_hh, Hp, W_out, b_out, (float*)d_out);
}